// Round 1
// baseline (137.412 us; speedup 1.0000x reference)
//
#include <hip/hip_runtime.h>
#include <stdint.h>

typedef __attribute__((ext_vector_type(8))) short short8;   // 8 bf16 (4 VGPRs) MFMA operand
typedef __attribute__((ext_vector_type(4))) float floatx4;  // MFMA accumulator

#define NPTS 256   // points per group
#define DIM  256   // feature dim
#define TILE 128   // output tile per block
#define BK   32    // K-step
#define LDSS 40    // LDS row stride (32 + 8 pad -> 80B rows, 2-way bank aliasing = free)

static __device__ __forceinline__ uint16_t bf16_rne(float f) {
    uint32_t u = __builtin_bit_cast(uint32_t, f);
    u += 0x7FFFu + ((u >> 16) & 1u);
    return (uint16_t)(u >> 16);
}
static __device__ __forceinline__ float bf16f(uint16_t h) {
    uint32_t u = ((uint32_t)h) << 16;
    return __builtin_bit_cast(float, u);
}
static __device__ __forceinline__ float trunc_bf16f(float f) {
    uint32_t u = __builtin_bit_cast(uint32_t, f) & 0xFFFF0000u;
    return __builtin_bit_cast(float, u);
}
static __device__ __forceinline__ uint32_t pack_trunc(float a, float b) {
    uint32_t ua = __builtin_bit_cast(uint32_t, a);
    uint32_t ub = __builtin_bit_cast(uint32_t, b);
    return (ua >> 16) | (ub & 0xFFFF0000u);
}

// ---------------------------------------------------------------------------
// Kernel 1: per-point squared norms of the bf16-rounded points.
// BIG=true additionally writes bf16-converted X,Y to workspace (RNE rounding).
// BIG=false uses truncation rounding (must match the GEMM's inline conversion).
// One wave per point; 16 points per 256-thread block.
// ---------------------------------------------------------------------------
template<bool BIG>
__global__ __launch_bounds__(256)
void mmd_norms(const float* __restrict__ X, const float* __restrict__ Y,
               float* __restrict__ x2, float* __restrict__ y2,
               uint16_t* __restrict__ Xb, uint16_t* __restrict__ Yb, int npts) {
    int lane = threadIdx.x & 63;
    int wv   = threadIdx.x >> 6;
    int pblk = blockIdx.x * 16;
    #pragma unroll
    for (int r = 0; r < 4; ++r) {
        int p = pblk + wv + 4 * r;           // block never straddles X/Y (npts % 16 == 0)
        const float* src; float* dst; uint16_t* bdst; int pl;
        if (p < npts) { src = X; dst = x2; bdst = Xb; pl = p; }
        else          { src = Y; dst = y2; bdst = Yb; pl = p - npts; }
        const float4 v = *(const float4*)(src + (size_t)pl * DIM + lane * 4);
        float f0, f1, f2, f3;
        if (BIG) {
            uint16_t b0 = bf16_rne(v.x), b1 = bf16_rne(v.y),
                     b2 = bf16_rne(v.z), b3 = bf16_rne(v.w);
            f0 = bf16f(b0); f1 = bf16f(b1); f2 = bf16f(b2); f3 = bf16f(b3);
            ushort4 pk = { b0, b1, b2, b3 };
            *(ushort4*)(bdst + (size_t)pl * DIM + lane * 4) = pk;
        } else {
            f0 = trunc_bf16f(v.x); f1 = trunc_bf16f(v.y);
            f2 = trunc_bf16f(v.z); f3 = trunc_bf16f(v.w);
        }
        float ssq = f0 * f0 + f1 * f1 + f2 * f2 + f3 * f3;
        #pragma unroll
        for (int off = 32; off; off >>= 1) ssq += __shfl_down(ssq, off);
        if (lane == 0) dst[pl] = ssq;
    }
}

// ---------------------------------------------------------------------------
// Kernel 2: per (group, tile) 128x128 Gram tile via bf16 MFMA, fused distance
// epilogue + reduction + single atomicAdd.
// grid = (10, G): tiles 0..3 = XY (w=+1), 4..6 = XX upper (w=-0.5/-1/-0.5),
// 7..9 = YY upper. Off-diagonal symmetric tiles counted twice via weight.
// ---------------------------------------------------------------------------
template<bool FROM_BF16>
__global__ __launch_bounds__(256)
void mmd_gemm(const float* __restrict__ X, const float* __restrict__ Y,
              const uint16_t* __restrict__ Xb, const uint16_t* __restrict__ Yb,
              const float* __restrict__ x2, const float* __restrict__ y2,
              float* __restrict__ out, float scale) {
    int g = blockIdx.y;
    int t = blockIdx.x;

    int ptype, ti, tj; float w;
    if (t < 4)      { ptype = 0; ti = t >> 1; tj = t & 1; w = 1.0f; }
    else if (t < 7) { int u = t - 4; ptype = 1; ti = (u == 2); tj = (u >= 1); w = (u == 1) ? -1.0f : -0.5f; }
    else            { int u = t - 7; ptype = 2; ti = (u == 2); tj = (u >= 1); w = (u == 1) ? -1.0f : -0.5f; }

    const float *Pf, *Qf, *rn_g, *cn_g;
    const uint16_t *Pb, *Qb;
    if (ptype == 0)      { Pf = X; Qf = Y; Pb = Xb; Qb = Yb; rn_g = x2; cn_g = y2; }
    else if (ptype == 1) { Pf = X; Qf = X; Pb = Xb; Qb = Xb; rn_g = x2; cn_g = x2; }
    else                 { Pf = Y; Qf = Y; Pb = Yb; Qb = Yb; rn_g = y2; cn_g = y2; }
    const bool symdiag = (ptype != 0) && (ti == tj);

    const size_t prow0 = (size_t)g * NPTS + (size_t)ti * TILE;
    const size_t qrow0 = (size_t)g * NPTS + (size_t)tj * TILE;

    __shared__ uint16_t As[TILE * LDSS];
    __shared__ uint16_t Bs[TILE * LDSS];
    __shared__ float rnorm[TILE];
    __shared__ float cnorm[TILE];
    __shared__ float wpart[4];

    const int tid  = threadIdx.x;
    const int lane = tid & 63;
    const int wv   = tid >> 6;
    const int wrow = (wv >> 1) * 64;
    const int wcol = (wv & 1) * 64;
    const int quad = lane >> 4;
    const int l15  = lane & 15;

    floatx4 acc[4][4];
    #pragma unroll
    for (int i = 0; i < 4; ++i)
        #pragma unroll
        for (int j = 0; j < 4; ++j) acc[i][j] = (floatx4)0.0f;

    for (int kk = 0; kk < DIM; kk += BK) {
        __syncthreads();
        if (FROM_BF16) {
            // stage 128x32 bf16 tiles: 2 x 16B granules per thread per matrix
            #pragma unroll
            for (int i = 0; i < 2; ++i) {
                int gg = tid + i * 256;              // 0..511 granules of 8 bf16
                int row = gg >> 2, c0 = (gg & 3) * 8;
                *(short8*)&As[row * LDSS + c0] =
                    *(const short8*)(Pb + (prow0 + row) * DIM + kk + c0);
                *(short8*)&Bs[row * LDSS + c0] =
                    *(const short8*)(Qb + (qrow0 + row) * DIM + kk + c0);
            }
        } else {
            // stage from fp32 with cheap truncation-convert (matches mmd_norms<false>)
            #pragma unroll
            for (int i = 0; i < 4; ++i) {
                int f = tid + i * 256;               // float4 index 0..1023
                int row = f >> 3, c0 = (f & 7) * 4;
                float4 v = *(const float4*)(Pf + (prow0 + row) * DIM + kk + c0);
                uint2 pk = { pack_trunc(v.x, v.y), pack_trunc(v.z, v.w) };
                *(uint2*)&As[row * LDSS + c0] = pk;
                v = *(const float4*)(Qf + (qrow0 + row) * DIM + kk + c0);
                uint2 pk2 = { pack_trunc(v.x, v.y), pack_trunc(v.z, v.w) };
                *(uint2*)&Bs[row * LDSS + c0] = pk2;
            }
        }
        __syncthreads();

        short8 af[4], bfr[4];
        #pragma unroll
        for (int mi = 0; mi < 4; ++mi)
            af[mi] = *(const short8*)&As[(wrow + mi * 16 + l15) * LDSS + quad * 8];
        #pragma unroll
        for (int ni = 0; ni < 4; ++ni)
            bfr[ni] = *(const short8*)&Bs[(wcol + ni * 16 + l15) * LDSS + quad * 8];
        #pragma unroll
        for (int mi = 0; mi < 4; ++mi)
            #pragma unroll
            for (int ni = 0; ni < 4; ++ni)
                acc[mi][ni] = __builtin_amdgcn_mfma_f32_16x16x32_bf16(
                    af[mi], bfr[ni], acc[mi][ni], 0, 0, 0);
    }

    // stage the 128 row-norms and 128 col-norms for this tile
    __syncthreads();
    if (tid < TILE) rnorm[tid] = rn_g[prow0 + tid];
    else            cnorm[tid - TILE] = cn_g[qrow0 + tid - TILE];
    __syncthreads();

    // fused epilogue: d = sqrt(max(x2_i + y2_j - 2 S_ij, 0)), zero diagonal for XX/YY
    float lsum = 0.0f;
    #pragma unroll
    for (int mi = 0; mi < 4; ++mi) {
        #pragma unroll
        for (int i = 0; i < 4; ++i) {
            int r = wrow + mi * 16 + quad * 4 + i;   // C/D layout: row=(lane>>4)*4+reg
            float rv = rnorm[r];
            #pragma unroll
            for (int ni = 0; ni < 4; ++ni) {
                int c = wcol + ni * 16 + l15;        // C/D layout: col=lane&15
                float d2 = rv + cnorm[c] - 2.0f * acc[mi][ni][i];
                d2 = fmaxf(d2, 0.0f);
                float s = sqrtf(d2);
                if (symdiag && (r == c)) s = 0.0f;
                lsum += s;
            }
        }
    }
    #pragma unroll
    for (int off = 32; off; off >>= 1) lsum += __shfl_down(lsum, off);
    if (lane == 0) wpart[wv] = lsum;
    __syncthreads();
    if (tid == 0) {
        float bs = wpart[0] + wpart[1] + wpart[2] + wpart[3];
        atomicAdd(out, bs * (w * scale));
    }
}

// ---------------------------------------------------------------------------
extern "C" void kernel_launch(void* const* d_in, const int* in_sizes, int n_in,
                              void* d_out, int out_size, void* d_ws, size_t ws_size,
                              hipStream_t stream) {
    const float* X = (const float*)d_in[0];
    const float* Y = (const float*)d_in[1];
    const int total_elems = in_sizes[0];          // G*NPTS*DIM
    const int npts = total_elems / DIM;           // 32768
    const int G = npts / NPTS;                    // 128

    float* x2 = (float*)d_ws;
    float* y2 = x2 + npts;
    uint16_t* Xb = (uint16_t*)(y2 + npts);
    uint16_t* Yb = Xb + (size_t)total_elems;

    const size_t need_big = (size_t)npts * 2 * sizeof(float)
                          + (size_t)total_elems * 2 * sizeof(uint16_t);
    const bool big = ws_size >= need_big;

    float* out = (float*)d_out;
    hipMemsetAsync(out, 0, sizeof(float) * out_size, stream);

    const int nblk = (2 * npts) / 16;
    if (big) mmd_norms<true ><<<nblk, 256, 0, stream>>>(X, Y, x2, y2, Xb, Yb, npts);
    else     mmd_norms<false><<<nblk, 256, 0, stream>>>(X, Y, x2, y2, Xb, Yb, npts);

    const float scale = 1.0f / ((float)NPTS * (float)NPTS * (float)G);
    dim3 grid(10, G);
    if (big) mmd_gemm<true ><<<grid, 256, 0, stream>>>(X, Y, Xb, Yb, x2, y2, out, scale);
    else     mmd_gemm<false><<<grid, 256, 0, stream>>>(X, Y, Xb, Yb, x2, y2, out, scale);
}